// Round 1
// baseline (116.144 us; speedup 1.0000x reference)
//
#include <hip/hip_runtime.h>

// PatchIoULoss: reference computes IoU loss over the single 64x64 top-left
// patch (range(0,B=16,64) -> [0], range(0,C=1,64) -> [0]) of each batch image.
// Shapes fixed by setup_inputs(): pred/target (16,1,1024,1024) fp32.
// Per batch b: iand = sum(p*t), ior = sum(p)+sum(t)-iand over the 64x64 patch;
// out scalar = sum_b (1 - iand/ior).

#define B_   16
#define HW_  (1024 * 1024)   // per-batch plane stride
#define WROW 1024            // row stride

// Stage 1: 64 blocks (4 per batch), 256 threads. Each thread: one float4 per
// array. Writes partial (sum_p, sum_t, sum_pt) per block to ws[j*3 ..].
__global__ __launch_bounds__(256)
void patch_iou_partial(const float* __restrict__ pred,
                       const float* __restrict__ targ,
                       float* __restrict__ ws) {
    const int j = blockIdx.x;        // 0..63
    const int b = j >> 2;            // batch
    const int q = j & 3;             // row quarter (16 rows each)
    const int t = threadIdx.x;       // 0..255

    // 256 threads cover 16 rows x 16 float4-cols (64 floats/row)
    const int row  = (q << 4) + (t >> 4);   // 0..63
    const int col4 = t & 15;                // float4 column
    const size_t base = (size_t)b * HW_ + (size_t)row * WROW + (size_t)(col4 << 2);

    const float4 p  = *(const float4*)(pred + base);
    const float4 tg = *(const float4*)(targ + base);

    float sp  = p.x + p.y + p.z + p.w;
    float st  = tg.x + tg.y + tg.z + tg.w;
    float spt = p.x * tg.x + p.y * tg.y + p.z * tg.z + p.w * tg.w;

    // wave (64-lane) shuffle reduce
    #pragma unroll
    for (int off = 32; off > 0; off >>= 1) {
        sp  += __shfl_down(sp,  off, 64);
        st  += __shfl_down(st,  off, 64);
        spt += __shfl_down(spt, off, 64);
    }

    __shared__ float red[3][4];
    const int wave = t >> 6;
    const int lane = t & 63;
    if (lane == 0) {
        red[0][wave] = sp;
        red[1][wave] = st;
        red[2][wave] = spt;
    }
    __syncthreads();
    if (t == 0) {
        const float a = red[0][0] + red[0][1] + red[0][2] + red[0][3];
        const float c = red[1][0] + red[1][1] + red[1][2] + red[1][3];
        const float d = red[2][0] + red[2][1] + red[2][2] + red[2][3];
        ws[j * 3 + 0] = a;
        ws[j * 3 + 1] = c;
        ws[j * 3 + 2] = d;
    }
}

// Stage 2: one wave. Lane b<16 combines its batch's 4 partial triples,
// computes 1 - iand/ior, shuffle-reduces across lanes, lane 0 stores scalar.
__global__ __launch_bounds__(64)
void patch_iou_final(const float* __restrict__ ws, float* __restrict__ out) {
    const int lane = threadIdx.x;    // 0..63
    float term = 0.0f;
    if (lane < B_) {
        float sp = 0.0f, st = 0.0f, spt = 0.0f;
        #pragma unroll
        for (int q = 0; q < 4; ++q) {
            const int j = (lane << 2) + q;
            sp  += ws[j * 3 + 0];
            st  += ws[j * 3 + 1];
            spt += ws[j * 3 + 2];
        }
        const float ior = st + sp - spt;
        term = 1.0f - spt / ior;
    }
    // reduce 16 meaningful lanes (others are 0) — offsets 8..1 suffice, but
    // full 32..1 is also correct; keep 8..1 for fewer shuffles.
    #pragma unroll
    for (int off = 8; off > 0; off >>= 1) {
        term += __shfl_down(term, off, 64);
    }
    if (lane == 0) out[0] = term;
}

extern "C" void kernel_launch(void* const* d_in, const int* in_sizes, int n_in,
                              void* d_out, int out_size, void* d_ws, size_t ws_size,
                              hipStream_t stream) {
    const float* pred = (const float*)d_in[0];
    const float* targ = (const float*)d_in[1];
    float* out = (float*)d_out;
    float* ws  = (float*)d_ws;   // uses 64*3*4 = 768 bytes

    patch_iou_partial<<<64, 256, 0, stream>>>(pred, targ, ws);
    patch_iou_final<<<1, 64, 0, stream>>>(ws, out);
}